// Round 1
// baseline (247.975 us; speedup 1.0000x reference)
//
#include <hip/hip_runtime.h>
#include <math.h>

// ---------------- problem constants ----------------
constexpr int B   = 16;
constexpr int H   = 512, W = 512;
constexpr int HW  = H * W;          // 262144
constexpr int P4  = 128;            // after 4x4 block sum
constexpr int P4N = P4 * P4;        // 16384
constexpr int P8  = 64;             // after 8x8 block sum
constexpr int P8N = P8 * P8;        // 4096
constexpr int NIMG = 2 * B;         // pred images 0..15, gt images 16..31

// Sinkhorn K = exp(-10*d^2) separable taps
constexpr float KW1 = 4.5399929762484854e-05f;  // exp(-10)
constexpr float KW2 = 4.2483542552915889e-18f;  // exp(-40)

// ---------------- workspace layout (float offsets) ----------------
constexpr size_t OFF_P4   = 0;                              // [32][128][128]
constexpr size_t OFF_HB   = OFF_P4  + (size_t)NIMG * P4N;   // h-conv temp
constexpr size_t OFF_CV   = OFF_HB  + (size_t)NIMG * P4N;   // full conv result
constexpr size_t OFF_P8   = OFF_CV  + (size_t)NIMG * P4N;   // [32][64][64]
constexpr size_t OFF_TOT  = OFF_P8  + (size_t)NIMG * P8N;   // 32 raw batch sums
constexpr size_t OFF_CSUM = OFF_TOT + 32;                   // 32 conv sums

// ---------------- init: zero accumulators ----------------
__global__ void k_init(float* __restrict__ out, int out_size, float* __restrict__ ws) {
    int t = threadIdx.x;
    for (int i = t; i < out_size; i += 256) out[i] = 0.f;
    if (t < 64) ws[OFF_TOT + t] = 0.f;   // covers TOT(32) + CSUM(32)
}

// ---------------- 4x4 block sums of pred & gt ----------------
__global__ void k_block4(const float* __restrict__ pred, const float* __restrict__ gt,
                         float* __restrict__ ws) {
    int gid = blockIdx.x * 256 + threadIdx.x;     // [0, 32*16384)
    int img = gid >> 14;
    int rem = gid & (P4N - 1);
    int by = rem >> 7, bx = rem & 127;
    const float* src = (img < B) ? (pred + (size_t)img * HW)
                                 : (gt + (size_t)(img - B) * HW);
    const float4* s4 = reinterpret_cast<const float4*>(src);
    int base = (4 * by) * (W / 4) + bx;           // float4 index
    float s = 0.f;
#pragma unroll
    for (int r = 0; r < 4; r++) {
        float4 v = s4[base + r * (W / 4)];
        s += v.x + v.y + v.z + v.w;
    }
    ws[OFF_P4 + gid] = s;
}

// ---------------- 2x2 -> p8 + per-image raw totals ----------------
__global__ void k_block8(float* __restrict__ ws) {
    int gid = blockIdx.x * 256 + threadIdx.x;     // [0, 32*4096)
    int img = gid >> 12;
    int rem = gid & (P8N - 1);
    int y = rem >> 6, x = rem & 63;
    const float2* p2 = reinterpret_cast<const float2*>(ws + OFF_P4 + (size_t)img * P4N);
    float2 t0 = p2[y * 128 + x];
    float2 t1 = p2[y * 128 + 64 + x];
    float s = t0.x + t0.y + t1.x + t1.y;
    ws[OFF_P8 + gid] = s;
    // block (256 thr, single img) reduce -> totals
    float part = s;
#pragma unroll
    for (int o = 32; o > 0; o >>= 1) part += __shfl_down(part, o, 64);
    __shared__ float r[4];
    int lane = threadIdx.x & 63, wid = threadIdx.x >> 6;
    if (lane == 0) r[wid] = part;
    __syncthreads();
    if (threadIdx.x == 0)
        atomicAdd(&ws[OFF_TOT + img], r[0] + r[1] + r[2] + r[3]);
}

// ---------------- count loss (smooth L1) ----------------
__global__ void k_count(const float* __restrict__ ws, const int* __restrict__ gt_counts,
                        const int* __restrict__ cell_area, float* __restrict__ out) {
    int b = threadIdx.x;
    if (b >= B) return;
    int cv = *cell_area;
    // robust: python int -> int bits; if it looks like float bits, reinterpret
    float ca = (cv >= 1 && cv < 16777216) ? (float)cv : __int_as_float(cv);
    float pc = fmaxf(ws[OFF_TOT + b] / ca, 0.f);
    float d = fabsf(pc - (float)gt_counts[b]);
    float l = (d < 10.f) ? (0.05f * d * d) : (d - 5.f);
    atomicAdd(out, 3.0f * l / (float)B);
}

// ---------------- Gaussian 1D weights helper ----------------
__device__ __forceinline__ float gw_fill(float* w, int t) {
    if (t < 49) {
        float x = (float)(t - 24);
        w[t] = __expf(-x * x / 128.f) ; // sigma=8 -> 2*sigma^2=128; exact enough? use expf
    }
    return 0.f;
}

// ---------------- horizontal 49-tap Gaussian ----------------
__global__ void k_hconv(float* __restrict__ ws) {
    __shared__ float w[49];
    int t = threadIdx.x;
    if (t < 49) {
        float x = (float)(t - 24);
        w[t] = expf(-x * x / 128.f);
    }
    __syncthreads();
    float norm = 0.f;
#pragma unroll
    for (int i = 0; i < 49; i++) norm += w[i];
    float inv = 1.f / norm;

    int gid = blockIdx.x * 256 + t;               // [0, 32*16384)
    int img = gid >> 14;
    int rem = gid & (P4N - 1);
    int y = rem >> 7, x = rem & 127;
    const float* in = ws + OFF_P4 + (size_t)img * P4N + (size_t)y * P4;
    float s = 0.f;
    for (int k = 0; k < 49; k++) {
        int xx = x + k - 24;
        if (xx >= 0 && xx < P4) s += w[k] * in[xx];
    }
    ws[OFF_HB + gid] = s * inv;
}

// ---------------- vertical 49-tap Gaussian + conv sums ----------------
__global__ void k_vconv(float* __restrict__ ws) {
    __shared__ float w[49];
    int t = threadIdx.x;
    if (t < 49) {
        float x = (float)(t - 24);
        w[t] = expf(-x * x / 128.f);
    }
    __syncthreads();
    float norm = 0.f;
#pragma unroll
    for (int i = 0; i < 49; i++) norm += w[i];
    float inv = 1.f / norm;

    int gid = blockIdx.x * 256 + t;
    int img = gid >> 14;
    int rem = gid & (P4N - 1);
    int y = rem >> 7, x = rem & 127;
    const float* in = ws + OFF_HB + (size_t)img * P4N + x;
    float s = 0.f;
    for (int k = 0; k < 49; k++) {
        int yy = y + k - 24;
        if (yy >= 0 && yy < P4) s += w[k] * in[(size_t)yy * P4];
    }
    s *= inv;
    ws[OFF_CV + gid] = s;
    // reduce conv sum per image (block is within one image)
    float part = s;
#pragma unroll
    for (int o = 32; o > 0; o >>= 1) part += __shfl_down(part, o, 64);
    __shared__ float r[4];
    int lane = t & 63, wid = t >> 6;
    if (lane == 0) r[wid] = part;
    __syncthreads();
    if (t == 0)
        atomicAdd(&ws[OFF_CSUM + img], r[0] + r[1] + r[2] + r[3]);
}

// ---------------- KL + L2 over normalized density maps ----------------
__global__ void k_kll2(const float* __restrict__ ws, float* __restrict__ out) {
    int gid = blockIdx.x * 256 + threadIdx.x;     // [0, 16*16384)
    int b = gid >> 14;
    int rem = gid & (P4N - 1);
    float ps = ws[OFF_CV + (size_t)b * P4N + rem];
    float gs = ws[OFF_CV + (size_t)(B + b) * P4N + rem];
    float sp = fmaxf(ws[OFF_CSUM + b], 1e-8f);
    float sg = fmaxf(ws[OFF_CSUM + B + b], 1e-8f);
    float pn = ps / sp, gn = gs / sg;
    float kl = gn * logf((gn + 1e-8f) / (pn + 1e-8f));
    float d = pn - gn;
    float part = kl + d * d;
#pragma unroll
    for (int o = 32; o > 0; o >>= 1) part += __shfl_down(part, o, 64);
    __shared__ float r[4];
    int lane = threadIdx.x & 63, wid = threadIdx.x >> 6;
    if (lane == 0) r[wid] = part;
    __syncthreads();
    if (threadIdx.x == 0)
        atomicAdd(out, 0.5f * (r[0] + r[1] + r[2] + r[3]) / (float)B);
}

// ---------------- Sinkhorn OT: one workgroup per batch ----------------
__global__ void __launch_bounds__(1024) k_ot(const float* __restrict__ ws,
                                             float* __restrict__ out) {
    __shared__ float u[P8N], v[P8N], tb[P8N];
    int b = blockIdx.x;
    int tid = threadIdx.x;
    const float* ap = ws + OFF_P8 + (size_t)b * P8N;
    const float* bp = ws + OFF_P8 + (size_t)(B + b) * P8N;
    float asum = fmaxf(ws[OFF_TOT + b], 1e-8f);
    float bsum = fmaxf(ws[OFF_TOT + B + b], 1e-8f);
    float ar[4], br[4];
#pragma unroll
    for (int j = 0; j < 4; j++) {
        int p = tid + j * 1024;
        ar[j] = ap[p] / asum;
        br[j] = bp[p] / bsum;
        u[p] = 1.f;
    }
    __syncthreads();

    for (int it = 0; it < 50; it++) {
        // tb = Hconv(u)
#pragma unroll
        for (int j = 0; j < 4; j++) {
            int p = tid + j * 1024, x = p & 63;
            float s = u[p];
            s += KW1 * ((x >= 1 ? u[p - 1] : 0.f) + (x <= 62 ? u[p + 1] : 0.f));
            s += KW2 * ((x >= 2 ? u[p - 2] : 0.f) + (x <= 61 ? u[p + 2] : 0.f));
            tb[p] = s;
        }
        __syncthreads();
        // Ku = Vconv(tb); v = b / (Ku + eps)
#pragma unroll
        for (int j = 0; j < 4; j++) {
            int p = tid + j * 1024, y = p >> 6;
            float s = tb[p];
            s += KW1 * ((y >= 1 ? tb[p - 64] : 0.f) + (y <= 62 ? tb[p + 64] : 0.f));
            s += KW2 * ((y >= 2 ? tb[p - 128] : 0.f) + (y <= 61 ? tb[p + 128] : 0.f));
            v[p] = br[j] / (s + 1e-8f);
        }
        __syncthreads();
        // tb = Hconv(v)
#pragma unroll
        for (int j = 0; j < 4; j++) {
            int p = tid + j * 1024, x = p & 63;
            float s = v[p];
            s += KW1 * ((x >= 1 ? v[p - 1] : 0.f) + (x <= 62 ? v[p + 1] : 0.f));
            s += KW2 * ((x >= 2 ? v[p - 2] : 0.f) + (x <= 61 ? v[p + 2] : 0.f));
            tb[p] = s;
        }
        __syncthreads();
        // Kv = Vconv(tb); u = a / (Kv + eps)
#pragma unroll
        for (int j = 0; j < 4; j++) {
            int p = tid + j * 1024, y = p >> 6;
            float s = tb[p];
            s += KW1 * ((y >= 1 ? tb[p - 64] : 0.f) + (y <= 62 ? tb[p + 64] : 0.f));
            s += KW2 * ((y >= 2 ? tb[p - 128] : 0.f) + (y <= 61 ? tb[p + 128] : 0.f));
            u[p] = ar[j] / (s + 1e-8f);
        }
        __syncthreads();
    }

    // cost = sum_{n,m} u_n K_nm C_nm v_m  -> 5x5 stencil, center weight 0
    float wc[25];
#pragma unroll
    for (int dy = -2; dy <= 2; dy++)
#pragma unroll
        for (int dx = -2; dx <= 2; dx++) {
            int c = dy * dy + dx * dx;
            wc[(dy + 2) * 5 + (dx + 2)] = c ? expf(-10.f * (float)c) * (float)c : 0.f;
        }
    float part = 0.f;
#pragma unroll
    for (int j = 0; j < 4; j++) {
        int p = tid + j * 1024, y = p >> 6, x = p & 63;
        float s = 0.f;
#pragma unroll
        for (int dy = -2; dy <= 2; dy++) {
            int ny = y + dy;
            if (ny < 0 || ny >= 64) continue;
#pragma unroll
            for (int dx = -2; dx <= 2; dx++) {
                int nx = x + dx;
                if (nx < 0 || nx >= 64) continue;
                s += wc[(dy + 2) * 5 + (dx + 2)] * v[ny * 64 + nx];
            }
        }
        part += u[p] * s;
    }
#pragma unroll
    for (int o = 32; o > 0; o >>= 1) part += __shfl_down(part, o, 64);
    int lane = tid & 63, wid = tid >> 6;
    __syncthreads();            // done reading tb from loop; reuse for reduction
    if (lane == 0) tb[wid] = part;
    __syncthreads();
    if (tid == 0) {
        float s = 0.f;
        for (int i = 0; i < 16; i++) s += tb[i];
        if (asum > 0.5f && bsum > 0.5f)
            atomicAdd(out, 0.3f * s / (float)B);
    }
}

// ---------------- launcher ----------------
extern "C" void kernel_launch(void* const* d_in, const int* in_sizes, int n_in,
                              void* d_out, int out_size, void* d_ws, size_t ws_size,
                              hipStream_t stream) {
    const float* pred = (const float*)d_in[0];
    const float* gt   = (const float*)d_in[1];
    const int* gtc    = (const int*)d_in[2];
    const int* ca     = (const int*)d_in[3];
    float* out = (float*)d_out;
    float* ws  = (float*)d_ws;

    k_init<<<1, 256, 0, stream>>>(out, out_size, ws);
    k_block4<<<2048, 256, 0, stream>>>(pred, gt, ws);
    k_block8<<<512, 256, 0, stream>>>(ws);
    k_count<<<1, 64, 0, stream>>>(ws, gtc, ca, out);
    k_hconv<<<2048, 256, 0, stream>>>(ws);
    k_vconv<<<2048, 256, 0, stream>>>(ws);
    k_kll2<<<1024, 256, 0, stream>>>(ws, out);
    k_ot<<<16, 1024, 0, stream>>>(ws, out);
}

// Round 2
// 225.715 us; speedup vs baseline: 1.0986x; 1.0986x over previous
//
#include <hip/hip_runtime.h>
#include <math.h>

// ---------------- problem constants ----------------
constexpr int B   = 16;
constexpr int H   = 512, W = 512;
constexpr int HW  = H * W;          // 262144
constexpr int P4  = 128;            // after 4x4 block sum
constexpr int P4N = P4 * P4;        // 16384
constexpr int P8N = 64 * 64;        // 4096
constexpr int NIMG = 2 * B;

// Sinkhorn K = exp(-10*d^2): 1D taps beyond |d|=1 are < 5e-18 relative -> below
// fp32 rounding of the accumulator; 3-tap separable stencil is exact to fp32.
constexpr float KW1 = 4.5399929762484854e-05f;  // exp(-10)
constexpr float KC2 = 4.1223072448771156e-09f;  // 2*exp(-20)  (cost diag weight)

// ---------------- workspace layout (float offsets) ----------------
constexpr size_t OFF_P4   = 0;                              // [32][128][128]
constexpr size_t OFF_CV   = OFF_P4  + (size_t)NIMG * P4N;   // conv result
constexpr size_t OFF_P8   = OFF_CV  + (size_t)NIMG * P4N;   // [32][64][64]
constexpr size_t OFF_TOT  = OFF_P8  + (size_t)NIMG * P8N;   // 32 raw sums
constexpr size_t OFF_CSUM = OFF_TOT + 32;                   // 32 conv sums

__device__ __forceinline__ float bperm(int addr, float v) {
    return __int_as_float(__builtin_amdgcn_ds_bpermute(addr, __float_as_int(v)));
}

// ---------------- 4x4 block sums + zero accumulators ----------------
__global__ void k_pre(const float* __restrict__ pred, const float* __restrict__ gt,
                      float* __restrict__ ws, float* __restrict__ out, int out_size) {
    int t = threadIdx.x;
    if (blockIdx.x == 0) {
        for (int i = t; i < out_size; i += 256) out[i] = 0.f;
        if (t < 32) ws[OFF_TOT + t] = 0.f;
    }
    int gid = blockIdx.x * 256 + t;               // [0, 32*16384)
    int img = gid >> 14;
    int rem = gid & (P4N - 1);
    int by = rem >> 7, bx = rem & 127;
    const float* src = (img < B) ? (pred + (size_t)img * HW)
                                 : (gt + (size_t)(img - B) * HW);
    const float4* s4 = reinterpret_cast<const float4*>(src);
    int base = (4 * by) * (W / 4) + bx;
    float s = 0.f;
#pragma unroll
    for (int r = 0; r < 4; r++) {
        float4 v = s4[base + r * (W / 4)];
        s += v.x + v.y + v.z + v.w;
    }
    ws[OFF_P4 + gid] = s;
}

// ---------------- 2x2 -> p8 + per-image raw totals ----------------
__global__ void k_block8(float* __restrict__ ws) {
    int gid = blockIdx.x * 256 + threadIdx.x;     // [0, 32*4096)
    int img = gid >> 12;
    int rem = gid & (P8N - 1);
    int y = rem >> 6, x = rem & 63;
    const float2* p2 = reinterpret_cast<const float2*>(ws + OFF_P4 + (size_t)img * P4N);
    float2 t0 = p2[y * 128 + x];
    float2 t1 = p2[y * 128 + 64 + x];
    float s = t0.x + t0.y + t1.x + t1.y;
    ws[OFF_P8 + gid] = s;
    float part = s;
#pragma unroll
    for (int o = 32; o > 0; o >>= 1) part += __shfl_down(part, o, 64);
    __shared__ float r[4];
    int lane = threadIdx.x & 63, wid = threadIdx.x >> 6;
    if (lane == 0) r[wid] = part;
    __syncthreads();
    if (threadIdx.x == 0)
        atomicAdd(&ws[OFF_TOT + img], r[0] + r[1] + r[2] + r[3]);
}

// ---------------- fused 49-tap separable Gaussian (one wg per image) --------
// LDS tile row-swizzled: element (r,x) at r*128 + (x ^ (r&31)) -> both the
// row-wise writes (h-phase) and column-wise reads (v-phase) are conflict-free.
__global__ void __launch_bounds__(256) k_conv(float* __restrict__ ws) {
    __shared__ float hbuf[P4N];                   // 64 KB
    int img = blockIdx.x;
    int t = threadIdx.x;
    float wgt[49];
    float norm = 0.f;
#pragma unroll
    for (int k = 0; k < 49; k++) {
        float xx = (float)(k - 24);
        wgt[k] = expf(-xx * xx * (1.f / 128.f));
        norm += wgt[k];
    }
    float inv = 1.f / norm;
    const float* src = ws + OFF_P4 + (size_t)img * P4N;

    // ---- H phase: global -> LDS(swizzled) ----
    {
        int r = t >> 1, x0 = (t & 1) * 64;
        int sw = r & 31;
        for (int g = 0; g < 8; g++) {
            int xs = x0 + g * 8;
            float v[56];
#pragma unroll
            for (int j = 0; j < 56; j++) {
                int idx = xs - 24 + j;
                v[j] = (idx >= 0 && idx < 128) ? src[r * 128 + idx] : 0.f;
            }
#pragma unroll
            for (int i = 0; i < 8; i++) {
                float s = 0.f;
#pragma unroll
                for (int k = 0; k < 49; k++) s += wgt[k] * v[i + k];
                hbuf[r * 128 + ((xs + i) ^ sw)] = s * inv;
            }
        }
    }
    __syncthreads();

    // ---- V phase: LDS -> global + conv sum ----
    float part = 0.f;
    {
        int c = t & 127, rh = t >> 7;
        float* dst = ws + OFF_CV + (size_t)img * P4N;
        for (int g = 0; g < 8; g++) {
            int rs = rh * 64 + g * 8;
            float v[56];
#pragma unroll
            for (int j = 0; j < 56; j++) {
                int rr = rs - 24 + j;
                v[j] = (rr >= 0 && rr < 128) ? hbuf[rr * 128 + (c ^ (rr & 31))] : 0.f;
            }
#pragma unroll
            for (int i = 0; i < 8; i++) {
                float s = 0.f;
#pragma unroll
                for (int k = 0; k < 49; k++) s += wgt[k] * v[i + k];
                s *= inv;
                dst[(rs + i) * 128 + c] = s;
                part += s;
            }
        }
    }
#pragma unroll
    for (int o = 32; o > 0; o >>= 1) part += __shfl_down(part, o, 64);
    __syncthreads();                               // v-phase reads done
    if ((t & 63) == 0) hbuf[t >> 6] = part;
    __syncthreads();
    if (t == 0) ws[OFF_CSUM + img] = hbuf[0] + hbuf[1] + hbuf[2] + hbuf[3];
}

// ---------------- KL + L2 over normalized density maps ----------------
__global__ void k_kll2(const float* __restrict__ ws, float* __restrict__ out) {
    int gid = blockIdx.x * 256 + threadIdx.x;     // [0, 16*16384)
    int b = gid >> 14;
    int rem = gid & (P4N - 1);
    float ps = ws[OFF_CV + (size_t)b * P4N + rem];
    float gs = ws[OFF_CV + (size_t)(B + b) * P4N + rem];
    float sp = fmaxf(ws[OFF_CSUM + b], 1e-8f);
    float sg = fmaxf(ws[OFF_CSUM + B + b], 1e-8f);
    float pn = ps / sp, gn = gs / sg;
    float kl = gn * logf((gn + 1e-8f) / (pn + 1e-8f));
    float d = pn - gn;
    float part = kl + d * d;
#pragma unroll
    for (int o = 32; o > 0; o >>= 1) part += __shfl_down(part, o, 64);
    __shared__ float r[4];
    int lane = threadIdx.x & 63, wid = threadIdx.x >> 6;
    if (lane == 0) r[wid] = part;
    __syncthreads();
    if (threadIdx.x == 0)
        atomicAdd(out, 0.5f * (r[0] + r[1] + r[2] + r[3]) / (float)B);
}

// ---------------- Sinkhorn OT: 4 waves/batch, registers + bpermute ----------
// lane = column x (64), wave w owns rows 16w..16w+15 in registers.
// H-conv: cross-lane ds_bpermute (no barrier). V-conv: in-register, 1-row
// halo via LDS; 2 barriers per iteration (down from 4), double-buffered.
__global__ void __launch_bounds__(256) k_ot(const float* __restrict__ ws,
                                            const int* __restrict__ gtc,
                                            const int* __restrict__ carea,
                                            float* __restrict__ out) {
    __shared__ float tbA[8][64], tbB[8][64], red[4];
    int b = blockIdx.x;
    int lane = threadIdx.x & 63;
    int w = threadIdx.x >> 6;
    int r0 = w << 4;
    float rawA = ws[OFF_TOT + b], rawB = ws[OFF_TOT + B + b];
    float asum = fmaxf(rawA, 1e-8f), bsum = fmaxf(rawB, 1e-8f);
    float ai = 1.f / asum, bi = 1.f / bsum;
    const float* ap = ws + OFF_P8 + (size_t)b * P8N;
    const float* bp = ws + OFF_P8 + (size_t)(B + b) * P8N;
    float ar[16], br[16], cur[16], t[16], vv[16];
#pragma unroll
    for (int r = 0; r < 16; r++) {
        ar[r] = ap[(r0 + r) * 64 + lane] * ai;
        br[r] = bp[(r0 + r) * 64 + lane] * bi;
        cur[r] = 1.f;
    }
    int aL = ((lane - 1) & 63) << 2, aR = ((lane + 1) & 63) << 2;
    float wl = (lane == 0) ? 0.f : KW1;     // edge-masked H weights
    float wr = (lane == 63) ? 0.f : KW1;

    for (int it = 0; it < 50; it++) {
        // ---- v = b / (K u + eps) ----
#pragma unroll
        for (int r = 0; r < 16; r++) {
            float l = bperm(aL, cur[r]);
            float rg = bperm(aR, cur[r]);
            t[r] = fmaf(wl, l, fmaf(wr, rg, cur[r]));
        }
        tbA[2 * w][lane] = t[0];
        tbA[2 * w + 1][lane] = t[15];
        __syncthreads();
        {
            float tup = (w > 0) ? tbA[2 * w - 1][lane] : 0.f;
            float tdn = (w < 3) ? tbA[2 * w + 2][lane] : 0.f;
#pragma unroll
            for (int r = 0; r < 16; r++) {
                float up = r ? t[r - 1] : tup;
                float dn = (r < 15) ? t[r + 1] : tdn;
                float s = fmaf(KW1, up + dn, t[r]) + 1e-8f;
                cur[r] = br[r] * __builtin_amdgcn_rcpf(s);
            }
        }
        if (it == 49) {
#pragma unroll
            for (int r = 0; r < 16; r++) vv[r] = cur[r];
        }
        // ---- u = a / (K v + eps) ----
#pragma unroll
        for (int r = 0; r < 16; r++) {
            float l = bperm(aL, cur[r]);
            float rg = bperm(aR, cur[r]);
            t[r] = fmaf(wl, l, fmaf(wr, rg, cur[r]));
        }
        tbB[2 * w][lane] = t[0];
        tbB[2 * w + 1][lane] = t[15];
        __syncthreads();
        {
            float tup = (w > 0) ? tbB[2 * w - 1][lane] : 0.f;
            float tdn = (w < 3) ? tbB[2 * w + 2][lane] : 0.f;
#pragma unroll
            for (int r = 0; r < 16; r++) {
                float up = r ? t[r - 1] : tup;
                float dn = (r < 15) ? t[r + 1] : tdn;
                float s = fmaf(KW1, up + dn, t[r]) + 1e-8f;
                cur[r] = ar[r] * __builtin_amdgcn_rcpf(s);
            }
        }
    }

    // ---- cost = u . (K*C) v : 3x3 stencil (d2=1 w=e^-10, d2=2 w=2e^-20) ----
    __syncthreads();
    tbA[2 * w][lane] = vv[0];
    tbA[2 * w + 1][lane] = vv[15];
    __syncthreads();
    float vup = (w > 0) ? tbA[2 * w - 1][lane] : 0.f;
    float vdn = (w < 3) ? tbA[2 * w + 2][lane] : 0.f;
    float ml = (lane == 0) ? 0.f : 1.f;
    float mr = (lane == 63) ? 0.f : 1.f;
    float part = 0.f;
    float lm = bperm(aL, vup), rm = bperm(aR, vup);
    float l0 = bperm(aL, vv[0]), g0 = bperm(aR, vv[0]);
#pragma unroll
    for (int r = 0; r < 16; r++) {
        float nx = (r < 15) ? vv[r + 1] : vdn;
        float lp = bperm(aL, nx), rp = bperm(aR, nx);
        float up = r ? vv[r - 1] : vup;
        float sC = KW1 * (up + nx + ml * l0 + mr * g0)
                 + KC2 * (ml * (lm + lp) + mr * (rm + rp));
        part += cur[r] * sC;
        lm = l0; l0 = lp; rm = g0; g0 = rp;
    }
#pragma unroll
    for (int o = 32; o > 0; o >>= 1) part += __shfl_down(part, o, 64);
    if (lane == 0) red[w] = part;
    __syncthreads();
    if (threadIdx.x == 0) {
        float c = red[0] + red[1] + red[2] + red[3];
        float ot = (asum > 0.5f && bsum > 0.5f) ? c : 0.f;
        int cv = carea[0];
        float ca = (cv >= 1 && cv < 16777216) ? (float)cv : __int_as_float(cv);
        float pc = fmaxf(rawA / ca, 0.f);
        float d = fabsf(pc - (float)gtc[b]);
        float cl = (d < 10.f) ? (0.05f * d * d) : (d - 5.f);
        atomicAdd(out, 0.3f * ot * (1.f / 16.f) + 3.f * cl * (1.f / 16.f));
    }
}

// ---------------- launcher ----------------
extern "C" void kernel_launch(void* const* d_in, const int* in_sizes, int n_in,
                              void* d_out, int out_size, void* d_ws, size_t ws_size,
                              hipStream_t stream) {
    const float* pred = (const float*)d_in[0];
    const float* gt   = (const float*)d_in[1];
    const int* gtc    = (const int*)d_in[2];
    const int* ca     = (const int*)d_in[3];
    float* out = (float*)d_out;
    float* ws  = (float*)d_ws;

    k_pre<<<2048, 256, 0, stream>>>(pred, gt, ws, out, out_size);
    k_block8<<<512, 256, 0, stream>>>(ws);
    k_conv<<<32, 256, 0, stream>>>(ws);
    k_kll2<<<1024, 256, 0, stream>>>(ws, out);
    k_ot<<<16, 256, 0, stream>>>(ws, gtc, ca, out);
}

// Round 3
// 137.486 us; speedup vs baseline: 1.8036x; 1.6417x over previous
//
#include <hip/hip_runtime.h>
#include <math.h>

// ---------------- problem constants ----------------
constexpr int B   = 16;
constexpr int H   = 512, W = 512;
constexpr int HW  = H * W;          // 262144
constexpr int P4  = 128;            // after 4x4 block sum
constexpr int P4N = P4 * P4;        // 16384
constexpr int P8N = 64 * 64;        // 4096
constexpr int NIMG = 2 * B;

// Sinkhorn K = exp(-10*d^2): taps beyond |d|=1 (and eps^2 corners) are below
// fp32 rounding of the center term -> 5-point stencil is fp32-exact.
constexpr float KW1 = 4.5399929762484854e-05f;  // exp(-10)
constexpr float KC2 = 4.1223072448771156e-09f;  // 2*exp(-20) (diag K*C weight)

// ---------------- workspace layout (float offsets) ----------------
constexpr size_t OFF_P4   = 0;                              // [32][128][128]
constexpr size_t OFF_CV   = OFF_P4  + (size_t)NIMG * P4N;   // conv result
constexpr size_t OFF_P8   = OFF_CV  + (size_t)NIMG * P4N;   // [32][64][64]
constexpr size_t OFF_PART = OFF_P8  + (size_t)NIMG * P8N;   // [512] block partials
constexpr size_t OFF_CSUM = OFF_PART + 512;                 // [32] conv sums

// DPP wave-wide shifts (VALU pipe, zero-fill at wave edges).
// wave_shr:1 (0x138): lane i <- lane i-1  ("up" row neighbor, 0 at row 0)
// wave_shl:1 (0x130): lane i <- lane i+1  ("down" row neighbor, 0 at row 63)
__device__ __forceinline__ float dpp_up(float x) {
    return __int_as_float(__builtin_amdgcn_update_dpp(
        0, __float_as_int(x), 0x138, 0xf, 0xf, true));
}
__device__ __forceinline__ float dpp_dn(float x) {
    return __int_as_float(__builtin_amdgcn_update_dpp(
        0, __float_as_int(x), 0x130, 0xf, 0xf, true));
}

// ---------------- fused 4x4 + 8x8 block sums + partials ----------------
// 512 blocks x 256 threads; thread <-> one P8 cell (8x8 pixels).
__global__ void k_pre8(const float* __restrict__ pred, const float* __restrict__ gt,
                       float* __restrict__ ws, float* __restrict__ out, int out_size) {
    int tid = threadIdx.x, bx = blockIdx.x;
    if (bx == 0) {
        for (int i = tid; i < out_size; i += 256) out[i] = 0.f;
    }
    int gid = bx * 256 + tid;                 // [0, 32*4096)
    int img = gid >> 12;
    int rem = gid & (P8N - 1);
    int y = rem >> 6, x = rem & 63;
    const float* src = (img < B) ? (pred + (size_t)img * HW)
                                 : (gt + (size_t)(img - B) * HW);
    const float4* s4 = reinterpret_cast<const float4*>(src);
    int base = y * 8 * 128 + x * 2;
    float q00 = 0.f, q01 = 0.f, q10 = 0.f, q11 = 0.f;
#pragma unroll
    for (int r = 0; r < 8; r++) {
        float4 a0 = s4[base + r * 128];
        float4 a1 = s4[base + r * 128 + 1];
        float sa = a0.x + a0.y + a0.z + a0.w;
        float sb = a1.x + a1.y + a1.z + a1.w;
        if (r < 4) { q00 += sa; q01 += sb; } else { q10 += sa; q11 += sb; }
    }
    float* p4 = ws + OFF_P4 + (size_t)img * P4N;
    p4[(2 * y) * 128 + 2 * x]       = q00;
    p4[(2 * y) * 128 + 2 * x + 1]   = q01;
    p4[(2 * y + 1) * 128 + 2 * x]   = q10;
    p4[(2 * y + 1) * 128 + 2 * x + 1] = q11;
    float s8 = q00 + q01 + q10 + q11;
    ws[OFF_P8 + gid] = s8;
    // block partial (256 cells of one img) -> PART[bx], no atomics
    float part = s8;
#pragma unroll
    for (int o = 32; o > 0; o >>= 1) part += __shfl_down(part, o, 64);
    __shared__ float r4[4];
    int lane = tid & 63, wid = tid >> 6;
    if (lane == 0) r4[wid] = part;
    __syncthreads();
    if (tid == 0) ws[OFF_PART + bx] = r4[0] + r4[1] + r4[2] + r4[3];
}

// ---------------- fused 49-tap separable Gaussian (one wg per image) --------
__global__ void __launch_bounds__(1024) k_conv(float* __restrict__ ws) {
    __shared__ float hbuf[P4N];               // 64 KB, row-swizzled
    __shared__ float wlds[49];
    __shared__ float rs[16];
    int img = blockIdx.x, tid = threadIdx.x;
    if (tid < 49) {
        float xx = (float)(tid - 24);
        wlds[tid] = expf(-xx * xx * (1.f / 128.f));
    }
    __syncthreads();
    float norm = 0.f;
#pragma unroll
    for (int k = 0; k < 49; k++) norm += wlds[k];
    float inv = 1.f / norm;
    const float* src = ws + OFF_P4 + (size_t)img * P4N;

    // ---- H phase: 2048 units = 128 rows x 16 segs (8 outputs each) ----
#pragma unroll
    for (int g = 0; g < 2; g++) {
        int unit = g * 1024 + tid;
        int r = unit >> 4, seg = unit & 15, x0 = seg * 8;
        const float4* row4 = reinterpret_cast<const float4*>(src + (size_t)r * 128);
        float v[56];
#pragma unroll
        for (int j = 0; j < 14; j++) {
            int fx = (x0 - 24) / 4 + j;
            float4 t = (fx >= 0 && fx < 32) ? row4[fx] : make_float4(0.f, 0.f, 0.f, 0.f);
            v[4 * j] = t.x; v[4 * j + 1] = t.y; v[4 * j + 2] = t.z; v[4 * j + 3] = t.w;
        }
        float o8[8];
#pragma unroll
        for (int i = 0; i < 8; i++) o8[i] = 0.f;
#pragma unroll
        for (int k = 0; k < 49; k++) {
            float wk = wlds[k];
#pragma unroll
            for (int i = 0; i < 8; i++) o8[i] = fmaf(wk, v[i + k], o8[i]);
        }
        int sw = r & 31;
#pragma unroll
        for (int i = 0; i < 8; i++)
            hbuf[r * 128 + ((x0 + i) ^ sw)] = o8[i] * inv;
    }
    __syncthreads();

    // ---- V phase: 2048 units = 128 cols x 16 row-segs ----
    float part = 0.f;
    float* dst = ws + OFF_CV + (size_t)img * P4N;
#pragma unroll
    for (int g = 0; g < 2; g++) {
        int unit = g * 1024 + tid;
        int c = unit & 127, rseg = unit >> 7, r0 = rseg * 8;
        float v[56];
#pragma unroll
        for (int j = 0; j < 56; j++) {
            int rr = r0 - 24 + j;
            v[j] = (rr >= 0 && rr < 128) ? hbuf[rr * 128 + (c ^ (rr & 31))] : 0.f;
        }
        float o8[8];
#pragma unroll
        for (int i = 0; i < 8; i++) o8[i] = 0.f;
#pragma unroll
        for (int k = 0; k < 49; k++) {
            float wk = wlds[k];
#pragma unroll
            for (int i = 0; i < 8; i++) o8[i] = fmaf(wk, v[i + k], o8[i]);
        }
#pragma unroll
        for (int i = 0; i < 8; i++) {
            float s = o8[i] * inv;
            dst[(size_t)(r0 + i) * 128 + c] = s;
            part += s;
        }
    }
#pragma unroll
    for (int o = 32; o > 0; o >>= 1) part += __shfl_down(part, o, 64);
    int lane = tid & 63, wid = tid >> 6;
    if (lane == 0) rs[wid] = part;
    __syncthreads();
    if (tid == 0) {
        float s = 0.f;
#pragma unroll
        for (int i = 0; i < 16; i++) s += rs[i];
        ws[OFF_CSUM + img] = s;
    }
}

// ---------------- KL + L2 over normalized density maps ----------------
__global__ void k_kll2(const float* __restrict__ ws, float* __restrict__ out) {
    int idx = blockIdx.x * 256 + threadIdx.x;     // [0, 65536)
    int b = idx >> 12, rem = idx & 4095;
    const float4* cv4 = reinterpret_cast<const float4*>(ws + OFF_CV);
    float4 p = cv4[(size_t)b * 4096 + rem];
    float4 g = cv4[(size_t)(B + b) * 4096 + rem];
    float isp = 1.f / fmaxf(ws[OFF_CSUM + b], 1e-8f);
    float isg = 1.f / fmaxf(ws[OFF_CSUM + B + b], 1e-8f);
    float part = 0.f;
#pragma unroll
    for (int j = 0; j < 4; j++) {
        float pn = (j == 0 ? p.x : j == 1 ? p.y : j == 2 ? p.z : p.w) * isp;
        float gn = (j == 0 ? g.x : j == 1 ? g.y : j == 2 ? g.z : g.w) * isg;
        float d = pn - gn;
        part += gn * __logf((gn + 1e-8f) / (pn + 1e-8f)) + d * d;
    }
#pragma unroll
    for (int o = 32; o > 0; o >>= 1) part += __shfl_down(part, o, 64);
    __shared__ float r4[4];
    int lane = threadIdx.x & 63, wid = threadIdx.x >> 6;
    if (lane == 0) r4[wid] = part;
    __syncthreads();
    if (threadIdx.x == 0)
        atomicAdd(out, (0.5f / 16.f) * (r4[0] + r4[1] + r4[2] + r4[3]));
}

// ---------------- Sinkhorn matvec: lane=row, 8 cols/wave in registers ------
__device__ __forceinline__ void matvec(float* cur, const float* tgt,
                                       float* hL, float* hR, int w, int lane) {
    hL[w * 64 + lane] = cur[0];
    hR[w * 64 + lane] = cur[7];
    __syncthreads();
    float lh = (w > 0) ? hR[(w - 1) * 64 + lane] : 0.f;
    float rh = (w < 7) ? hL[(w + 1) * 64 + lane] : 0.f;
    float t[8];
    t[0] = fmaf(KW1, lh + cur[1], cur[0]);
#pragma unroll
    for (int c = 1; c < 7; c++) t[c] = fmaf(KW1, cur[c - 1] + cur[c + 1], cur[c]);
    t[7] = fmaf(KW1, cur[6] + rh, cur[7]);
#pragma unroll
    for (int c = 0; c < 8; c++) {
        float s = fmaf(KW1, dpp_up(t[c]) + dpp_dn(t[c]), t[c]) + 1e-8f;
        cur[c] = tgt[c] * __builtin_amdgcn_rcpf(s);
    }
}

// ---------------- Sinkhorn OT + count loss: 16 blocks x 512 ----------------
__global__ void __launch_bounds__(512) k_ot(const float* __restrict__ ws,
                                            const int* __restrict__ gtc,
                                            const int* __restrict__ carea,
                                            float* __restrict__ out) {
    __shared__ float smem[2 * 64 * 65];           // a/b staging, reused for halos
    __shared__ float rsum[8];
    int b = blockIdx.x, tid = threadIdx.x;
    int lane = tid & 63;                           // row
    int w = tid >> 6;                              // wave = column group
    float* hL0 = smem;            float* hR0 = smem + 512;
    float* hL1 = smem + 1024;     float* hR1 = smem + 1536;

    // raw totals from PART (uniform loads)
    const float* PART = ws + OFF_PART;
    float rawA = 0.f, rawB = 0.f;
#pragma unroll
    for (int j = 0; j < 16; j++) {
        rawA += PART[b * 16 + j];
        rawB += PART[(B + b) * 16 + j];
    }
    float asum = fmaxf(rawA, 1e-8f), bsum = fmaxf(rawB, 1e-8f);
    float ai = 1.f / asum, bi = 1.f / bsum;

    // stage a,b into padded LDS (coalesced), then extract transposed frags
    const float* ap = ws + OFF_P8 + (size_t)b * P8N;
    const float* bp = ws + OFF_P8 + (size_t)(B + b) * P8N;
    for (int i = tid; i < P8N; i += 512) {
        int r = i >> 6, c = i & 63;
        smem[r * 65 + c] = ap[i];
        smem[64 * 65 + r * 65 + c] = bp[i];
    }
    __syncthreads();
    float ar[8], br[8], cur[8], vv[8];
    int gc = w * 8;
#pragma unroll
    for (int c = 0; c < 8; c++) {
        ar[c] = smem[lane * 65 + gc + c] * ai;
        br[c] = smem[64 * 65 + lane * 65 + gc + c] * bi;
        cur[c] = 1.f;
    }
    __syncthreads();                               // protect halo reuse of smem

    for (int it = 0; it < 50; it++) {
        matvec(cur, br, hL0, hR0, w, lane);        // v = b / (K u)
        if (it == 49) {
#pragma unroll
            for (int c = 0; c < 8; c++) vv[c] = cur[c];
        }
        matvec(cur, ar, hL1, hR1, w, lane);        // u = a / (K v)
    }

    // ---- cost = u . (K*C) v ----
    hL0[w * 64 + lane] = vv[0];
    hR0[w * 64 + lane] = vv[7];
    __syncthreads();
    float V[10];
    V[0] = (w > 0) ? hR0[(w - 1) * 64 + lane] : 0.f;
    V[9] = (w < 7) ? hL0[(w + 1) * 64 + lane] : 0.f;
#pragma unroll
    for (int c = 0; c < 8; c++) V[c + 1] = vv[c];
    float U[10], D[10];
#pragma unroll
    for (int i = 0; i < 10; i++) { U[i] = dpp_up(V[i]); D[i] = dpp_dn(V[i]); }
    float part = 0.f;
#pragma unroll
    for (int c = 0; c < 8; c++) {
        float s = KW1 * (V[c] + V[c + 2] + U[c + 1] + D[c + 1])
                + KC2 * (U[c] + D[c] + U[c + 2] + D[c + 2]);
        part += cur[c] * s;
    }
#pragma unroll
    for (int o = 32; o > 0; o >>= 1) part += __shfl_down(part, o, 64);
    if (lane == 0) rsum[w] = part;
    __syncthreads();
    if (tid == 0) {
        float c = 0.f;
#pragma unroll
        for (int i = 0; i < 8; i++) c += rsum[i];
        float ot = (asum > 0.5f && bsum > 0.5f) ? c : 0.f;
        int cv = carea[0];
        float ca = (cv >= 1 && cv < 16777216) ? (float)cv : __int_as_float(cv);
        float pc = fmaxf(rawA / ca, 0.f);
        float d = fabsf(pc - (float)gtc[b]);
        float cl = (d < 10.f) ? (0.05f * d * d) : (d - 5.f);
        atomicAdd(out, 0.3f * ot * (1.f / 16.f) + 3.f * cl * (1.f / 16.f));
    }
}

// ---------------- launcher ----------------
extern "C" void kernel_launch(void* const* d_in, const int* in_sizes, int n_in,
                              void* d_out, int out_size, void* d_ws, size_t ws_size,
                              hipStream_t stream) {
    const float* pred = (const float*)d_in[0];
    const float* gt   = (const float*)d_in[1];
    const int* gtc    = (const int*)d_in[2];
    const int* ca     = (const int*)d_in[3];
    float* out = (float*)d_out;
    float* ws  = (float*)d_ws;

    k_pre8<<<512, 256, 0, stream>>>(pred, gt, ws, out, out_size);
    k_conv<<<32, 1024, 0, stream>>>(ws);
    k_kll2<<<256, 256, 0, stream>>>(ws, out);
    k_ot<<<16, 512, 0, stream>>>(ws, gtc, ca, out);
}

// Round 4
// 123.775 us; speedup vs baseline: 2.0034x; 1.1108x over previous
//
#include <hip/hip_runtime.h>
#include <math.h>

// ---------------- problem constants ----------------
constexpr int B   = 16;
constexpr int H   = 512, W = 512;
constexpr int HW  = H * W;          // 262144
constexpr int P4  = 128;            // after 4x4 block sum
constexpr int P4N = P4 * P4;        // 16384
constexpr int P8N = 64 * 64;        // 4096
constexpr int NIMG = 2 * B;

// Sinkhorn K = exp(-10*d^2): taps beyond |d|=1 are below fp32 rounding of the
// center term -> 5-point separable stencil is fp32-exact.
constexpr float KW1 = 4.5399929762484854e-05f;  // exp(-10)
constexpr float KC2 = 4.1223072448771156e-09f;  // 2*exp(-20) (diag K*C weight)

// ---------------- workspace layout (float offsets) ----------------
constexpr size_t OFF_P4   = 0;                              // [32][128][128]
constexpr size_t OFF_CV   = OFF_P4  + (size_t)NIMG * P4N;   // conv result
constexpr size_t OFF_P8   = OFF_CV  + (size_t)NIMG * P4N;   // [32][64][64]
constexpr size_t OFF_PART = OFF_P8  + (size_t)NIMG * P8N;   // [512] block partials
constexpr size_t OFF_CSUM = OFF_PART + 512;                 // [32] conv sums

// DPP wave-wide shifts (VALU pipe, zero-fill at wave edges).
__device__ __forceinline__ float dpp_up(float x) {          // lane i <- i-1 (col-1)
    return __int_as_float(__builtin_amdgcn_update_dpp(
        0, __float_as_int(x), 0x138, 0xf, 0xf, true));
}
__device__ __forceinline__ float dpp_dn(float x) {          // lane i <- i+1 (col+1)
    return __int_as_float(__builtin_amdgcn_update_dpp(
        0, __float_as_int(x), 0x130, 0xf, 0xf, true));
}

// ---------------- fused 4x4 + 8x8 block sums + partials ----------------
__global__ void k_pre8(const float* __restrict__ pred, const float* __restrict__ gt,
                       float* __restrict__ ws, float* __restrict__ out, int out_size) {
    int tid = threadIdx.x, bx = blockIdx.x;
    if (bx == 0) {
        for (int i = tid; i < out_size; i += 256) out[i] = 0.f;
    }
    int gid = bx * 256 + tid;                 // [0, 32*4096)
    int img = gid >> 12;
    int rem = gid & (P8N - 1);
    int y = rem >> 6, x = rem & 63;
    const float* src = (img < B) ? (pred + (size_t)img * HW)
                                 : (gt + (size_t)(img - B) * HW);
    const float4* s4 = reinterpret_cast<const float4*>(src);
    int base = y * 8 * 128 + x * 2;
    float q00 = 0.f, q01 = 0.f, q10 = 0.f, q11 = 0.f;
#pragma unroll
    for (int r = 0; r < 8; r++) {
        float4 a0 = s4[base + r * 128];
        float4 a1 = s4[base + r * 128 + 1];
        float sa = a0.x + a0.y + a0.z + a0.w;
        float sb = a1.x + a1.y + a1.z + a1.w;
        if (r < 4) { q00 += sa; q01 += sb; } else { q10 += sa; q11 += sb; }
    }
    float* p4 = ws + OFF_P4 + (size_t)img * P4N;
    p4[(2 * y) * 128 + 2 * x]         = q00;
    p4[(2 * y) * 128 + 2 * x + 1]     = q01;
    p4[(2 * y + 1) * 128 + 2 * x]     = q10;
    p4[(2 * y + 1) * 128 + 2 * x + 1] = q11;
    float s8 = q00 + q01 + q10 + q11;
    ws[OFF_P8 + gid] = s8;
    float part = s8;
#pragma unroll
    for (int o = 32; o > 0; o >>= 1) part += __shfl_down(part, o, 64);
    __shared__ float r4[4];
    int lane = tid & 63, wid = tid >> 6;
    if (lane == 0) r4[wid] = part;
    __syncthreads();
    if (tid == 0) ws[OFF_PART + bx] = r4[0] + r4[1] + r4[2] + r4[3];
}

// ---------------- mega kernel: blocks 0..31 conv, 32..47 Sinkhorn OT --------
__global__ void __launch_bounds__(512) k_mega(float* __restrict__ ws,
                                              const int* __restrict__ gtc,
                                              const int* __restrict__ carea,
                                              float* __restrict__ out) {
    __shared__ float sh[P4N + 80];            // conv: hbuf+weights+red | ot: halos+red
    int tid = threadIdx.x;
    int lane = tid & 63, w = tid >> 6;

    if (blockIdx.x < 32) {
        // ================= conv role: 49-tap separable Gaussian =============
        int img = blockIdx.x;
        float* hbuf = sh;                     // [16384] row-swizzled
        float* wlds = sh + P4N;               // [49]
        float* rs   = sh + P4N + 56;          // [8]
        if (tid < 49) {
            float xx = (float)(tid - 24);
            wlds[tid] = expf(-xx * xx * (1.f / 128.f));
        }
        __syncthreads();
        float norm = 0.f;
#pragma unroll
        for (int k = 0; k < 49; k++) norm += wlds[k];
        float inv = 1.f / norm;
        const float* src = ws + OFF_P4 + (size_t)img * P4N;

        // ---- H phase: 2048 units = 128 rows x 16 segs (8 outputs each) ----
#pragma unroll
        for (int g = 0; g < 4; g++) {
            int unit = g * 512 + tid;
            int r = unit >> 4, seg = unit & 15, x0 = seg * 8;
            const float4* row4 = reinterpret_cast<const float4*>(src + (size_t)r * 128);
            float v[56];
#pragma unroll
            for (int j = 0; j < 14; j++) {
                int fx = (x0 - 24) / 4 + j;
                float4 t = (fx >= 0 && fx < 32) ? row4[fx] : make_float4(0.f, 0.f, 0.f, 0.f);
                v[4 * j] = t.x; v[4 * j + 1] = t.y; v[4 * j + 2] = t.z; v[4 * j + 3] = t.w;
            }
            float o8[8];
#pragma unroll
            for (int i = 0; i < 8; i++) o8[i] = 0.f;
#pragma unroll
            for (int k = 0; k < 49; k++) {
                float wk = wlds[k];
#pragma unroll
                for (int i = 0; i < 8; i++) o8[i] = fmaf(wk, v[i + k], o8[i]);
            }
            int sw = r & 31;
#pragma unroll
            for (int i = 0; i < 8; i++)
                hbuf[r * 128 + ((x0 + i) ^ sw)] = o8[i] * inv;
        }
        __syncthreads();

        // ---- V phase: 2048 units = 128 cols x 16 row-segs ----
        float part = 0.f;
        float* dst = ws + OFF_CV + (size_t)img * P4N;
#pragma unroll
        for (int g = 0; g < 4; g++) {
            int unit = g * 512 + tid;
            int c = unit & 127, rseg = unit >> 7, r0 = rseg * 8;
            float v[56];
#pragma unroll
            for (int j = 0; j < 56; j++) {
                int rr = r0 - 24 + j;
                v[j] = (rr >= 0 && rr < 128) ? hbuf[rr * 128 + (c ^ (rr & 31))] : 0.f;
            }
            float o8[8];
#pragma unroll
            for (int i = 0; i < 8; i++) o8[i] = 0.f;
#pragma unroll
            for (int k = 0; k < 49; k++) {
                float wk = wlds[k];
#pragma unroll
                for (int i = 0; i < 8; i++) o8[i] = fmaf(wk, v[i + k], o8[i]);
            }
#pragma unroll
            for (int i = 0; i < 8; i++) {
                float s = o8[i] * inv;
                dst[(size_t)(r0 + i) * 128 + c] = s;
                part += s;
            }
        }
#pragma unroll
        for (int o = 32; o > 0; o >>= 1) part += __shfl_down(part, o, 64);
        if (lane == 0) rs[w] = part;
        __syncthreads();
        if (tid == 0) {
            float s = 0.f;
#pragma unroll
            for (int i = 0; i < 8; i++) s += rs[i];
            ws[OFF_CSUM + img] = s;
        }
    } else {
        // ================= OT role: Sinkhorn, 1 batch/block =================
        // lane = column, wave w owns rows 8w..8w+7 in registers; halo width 2
        // -> ONE barrier per iteration; col stencil via DPP (VALU, no LDS).
        int b = blockIdx.x - 32;
        int r0 = w << 3;
        float* H0 = sh;                        // halo parity 0: [4][8][64]
        float* H1 = sh + 2048;                 // halo parity 1
        float* rsum = sh + 4096;               // [8]

        const float* PART = ws + OFF_PART;
        float rawA = 0.f, rawB = 0.f;
#pragma unroll
        for (int j = 0; j < 16; j++) {
            rawA += PART[b * 16 + j];
            rawB += PART[(B + b) * 16 + j];
        }
        float asum = fmaxf(rawA, 1e-8f), bsum = fmaxf(rawB, 1e-8f);
        float ai = 1.f / asum, bi = 1.f / bsum;
        const float* ap = ws + OFF_P8 + (size_t)b * P8N;
        const float* bp = ws + OFF_P8 + (size_t)(B + b) * P8N;

        float ar[8], br10[10], cur[8], vr[10];
#pragma unroll
        for (int k = 0; k < 8; k++) {
            ar[k] = ap[(r0 + k) * 64 + lane] * ai;   // coalesced
            cur[k] = 1.f;
        }
#pragma unroll
        for (int i = 0; i < 10; i++) {
            int rr = r0 - 1 + i;
            br10[i] = (rr >= 0 && rr < 64) ? bp[rr * 64 + lane] * bi : 0.f;
        }

        for (int it = 0; it < 50; it++) {
            float* Hp = (it & 1) ? H1 : H0;
            Hp[(0 * 8 + w) * 64 + lane] = cur[0];
            Hp[(1 * 8 + w) * 64 + lane] = cur[1];
            Hp[(2 * 8 + w) * 64 + lane] = cur[6];
            Hp[(3 * 8 + w) * 64 + lane] = cur[7];
            __syncthreads();
            float uext[12];
            uext[0]  = w ? Hp[(2 * 8 + w - 1) * 64 + lane] : 0.f;   // row r0-2
            uext[1]  = w ? Hp[(3 * 8 + w - 1) * 64 + lane] : 0.f;   // row r0-1
#pragma unroll
            for (int k = 0; k < 8; k++) uext[2 + k] = cur[k];
            uext[10] = (w < 7) ? Hp[(0 * 8 + w + 1) * 64 + lane] : 0.f;
            uext[11] = (w < 7) ? Hp[(1 * 8 + w + 1) * 64 + lane] : 0.f;

            // v = b / (K u + eps) on rows r0-1..r0+8 (2 redundant)
            float tr[10];
#pragma unroll
            for (int i = 0; i < 10; i++)
                tr[i] = fmaf(KW1, uext[i] + uext[i + 2], uext[i + 1]);
#pragma unroll
            for (int i = 0; i < 10; i++) {
                float s = fmaf(KW1, dpp_up(tr[i]) + dpp_dn(tr[i]), tr[i]) + 1e-8f;
                vr[i] = br10[i] * __builtin_amdgcn_rcpf(s);
            }
            // u = a / (K v + eps) on rows r0..r0+7
            float t2[8];
#pragma unroll
            for (int k = 0; k < 8; k++)
                t2[k] = fmaf(KW1, vr[k] + vr[k + 2], vr[k + 1]);
#pragma unroll
            for (int k = 0; k < 8; k++) {
                float s = fmaf(KW1, dpp_up(t2[k]) + dpp_dn(t2[k]), t2[k]) + 1e-8f;
                cur[k] = ar[k] * __builtin_amdgcn_rcpf(s);
            }
        }

        // ---- cost = u . (K*C) v : 3x3 stencil; vr has the +-1 row halo ----
        float dL[10], dR[10];
#pragma unroll
        for (int i = 0; i < 10; i++) { dL[i] = dpp_up(vr[i]); dR[i] = dpp_dn(vr[i]); }
        float part = 0.f;
#pragma unroll
        for (int k = 0; k < 8; k++) {
            float s = KW1 * (vr[k] + vr[k + 2] + dL[k + 1] + dR[k + 1])
                    + KC2 * (dL[k] + dR[k] + dL[k + 2] + dR[k + 2]);
            part = fmaf(cur[k], s, part);
        }
#pragma unroll
        for (int o = 32; o > 0; o >>= 1) part += __shfl_down(part, o, 64);
        if (lane == 0) rsum[w] = part;
        __syncthreads();
        if (tid == 0) {
            float c = 0.f;
#pragma unroll
            for (int i = 0; i < 8; i++) c += rsum[i];
            float ot = (asum > 0.5f && bsum > 0.5f) ? c : 0.f;
            int cv = carea[0];
            float ca = (cv >= 1 && cv < 16777216) ? (float)cv : __int_as_float(cv);
            float pc = fmaxf(rawA / ca, 0.f);
            float d = fabsf(pc - (float)gtc[b]);
            float cl = (d < 10.f) ? (0.05f * d * d) : (d - 5.f);
            atomicAdd(out, 0.3f * ot * (1.f / 16.f) + 3.f * cl * (1.f / 16.f));
        }
    }
}

// ---------------- KL + L2 over normalized density maps ----------------
__global__ void k_kll2(const float* __restrict__ ws, float* __restrict__ out) {
    int idx = blockIdx.x * 256 + threadIdx.x;     // [0, 65536)
    int b = idx >> 12, rem = idx & 4095;
    const float4* cv4 = reinterpret_cast<const float4*>(ws + OFF_CV);
    float4 p = cv4[(size_t)b * 4096 + rem];
    float4 g = cv4[(size_t)(B + b) * 4096 + rem];
    float isp = 1.f / fmaxf(ws[OFF_CSUM + b], 1e-8f);
    float isg = 1.f / fmaxf(ws[OFF_CSUM + B + b], 1e-8f);
    float part = 0.f;
#pragma unroll
    for (int j = 0; j < 4; j++) {
        float pn = (j == 0 ? p.x : j == 1 ? p.y : j == 2 ? p.z : p.w) * isp;
        float gn = (j == 0 ? g.x : j == 1 ? g.y : j == 2 ? g.z : g.w) * isg;
        float d = pn - gn;
        part += gn * __logf((gn + 1e-8f) / (pn + 1e-8f)) + d * d;
    }
#pragma unroll
    for (int o = 32; o > 0; o >>= 1) part += __shfl_down(part, o, 64);
    __shared__ float r4[4];
    int lane = threadIdx.x & 63, wid = threadIdx.x >> 6;
    if (lane == 0) r4[wid] = part;
    __syncthreads();
    if (threadIdx.x == 0)
        atomicAdd(out, (0.5f / 16.f) * (r4[0] + r4[1] + r4[2] + r4[3]));
}

// ---------------- launcher ----------------
extern "C" void kernel_launch(void* const* d_in, const int* in_sizes, int n_in,
                              void* d_out, int out_size, void* d_ws, size_t ws_size,
                              hipStream_t stream) {
    const float* pred = (const float*)d_in[0];
    const float* gt   = (const float*)d_in[1];
    const int* gtc    = (const int*)d_in[2];
    const int* ca     = (const int*)d_in[3];
    float* out = (float*)d_out;
    float* ws  = (float*)d_ws;

    k_pre8<<<512, 256, 0, stream>>>(pred, gt, ws, out, out_size);
    k_mega<<<48, 512, 0, stream>>>(ws, gtc, ca, out);
    k_kll2<<<256, 256, 0, stream>>>(ws, out);
}